// Round 7
// baseline (1162.916 us; speedup 1.0000x reference)
//
#include <hip/hip_runtime.h>
#include <math.h>

#define BB 16
#define CC 1024
#define NN 16384
#define HID 128            // C / RATIO
#define GROUP 2            // batches per L3-blocked group (2*67MB = 134MB < 256MB L3)
#define NGROUPS (BB/GROUP)
#define SPLIT 16           // c-groups in k3/k4 partials
#define CROWS (CC/SPLIT)   // 64 rows per split
#define NSPL 16            // n-windows in k3 (window = 256 float4)
#define N4 (NN/4)          // 4096 float4 per row
#define EXPSHIFT 10.0f     // uniform shift inside softmax (exact math)
#define CG 8               // c-rows per block in k6

typedef float f4 __attribute__((ext_vector_type(4)));

// ---------------- K1: per-(b,c) mean & max over N (regular loads -> warm L3) ----------------
__global__ __launch_bounds__(256) void k1_pool(const float* __restrict__ x,
                                               float* __restrict__ meanp,
                                               float* __restrict__ maxp,
                                               int b0) {
    const int row = b0 * CC + blockIdx.x;       // covers GROUP*CC rows
    const int tid = threadIdx.x;
    const f4* xr = (const f4*)(x + (size_t)row * NN);
    float s = 0.f, m = -INFINITY;
    #pragma unroll
    for (int i = 0; i < 16; ++i) {
        f4 v = xr[tid + i * 256];               // regular load: retain in L3
        s += v.x + v.y + v.z + v.w;
        m = fmaxf(m, fmaxf(fmaxf(v.x, v.y), fmaxf(v.z, v.w)));
    }
    __shared__ float ss[4], sm[4];
    for (int off = 32; off > 0; off >>= 1) {
        s += __shfl_down(s, off, 64);
        m = fmaxf(m, __shfl_down(m, off, 64));
    }
    const int wave = tid >> 6, lane = tid & 63;
    if (lane == 0) { ss[wave] = s; sm[wave] = m; }
    __syncthreads();
    if (tid == 0) {
        float fs = ss[0] + ss[1] + ss[2] + ss[3];
        float fm = fmaxf(fmaxf(sm[0], sm[1]), fmaxf(sm[2], sm[3]));
        meanp[row] = fs * (1.0f / NN);
        maxp[row]  = fm;
    }
}

// ---------------- K2: shared MLP -> gate (one 1024-thr block per b) ----------------
__global__ __launch_bounds__(1024) void k2_gate(const float* __restrict__ meanp,
                                                const float* __restrict__ maxp,
                                                const float* __restrict__ w1,
                                                const float* __restrict__ w2,
                                                float* __restrict__ gate,
                                                int b0) {
    const int b = b0 + blockIdx.x;
    const int tid = threadIdx.x;
    __shared__ float sv[2][CC];
    __shared__ float hh[2][HID];
    __shared__ float h[HID];
    if (tid < CC) {
        sv[0][tid] = meanp[b * CC + tid];
        sv[1][tid] = maxp[b * CC + tid];
    }
    __syncthreads();
    {
        const int slot = tid >> 2;       // 0..255
        const int part = tid & 3;        // 0..3
        const int src  = slot >> 7;      // 0..1
        const int r    = slot & 127;
        const float* w1r = w1 + (size_t)r * CC;
        const float* svp = sv[src];
        float acc = 0.f;
        const int c0 = part * 256;
        #pragma unroll 8
        for (int c = c0; c < c0 + 256; ++c) acc = fmaf(w1r[c], svp[c], acc);
        acc += __shfl_xor(acc, 1, 64);
        acc += __shfl_xor(acc, 2, 64);
        if (part == 0) hh[src][r] = fmaxf(acc, 0.f);   // relu
    }
    __syncthreads();
    if (tid < HID) h[tid] = hh[0][tid] + hh[1][tid];
    __syncthreads();
    {
        const float* w2r = w2 + (size_t)tid * HID;
        float a = 0.f;
        #pragma unroll
        for (int r = 0; r < HID; ++r) a = fmaf(w2r[r], h[r], a);
        gate[b * CC + tid] = 1.0f / (1.0f + expf(-a));  // sigmoid
    }
}

// ---------------- K3: spatial weighted sum/max over C (x read hits L3) ----------------
__global__ __launch_bounds__(256) void k3_spatial(const float* __restrict__ x,
                                                  const float* __restrict__ gate,
                                                  float* __restrict__ psum,
                                                  float* __restrict__ pmax,
                                                  int b0) {
    const int npart = blockIdx.x;   // 0..NSPL-1
    const int split = blockIdx.y;   // 0..SPLIT-1
    const int b     = b0 + blockIdx.z;
    const int tid = threadIdx.x;
    __shared__ float g[CROWS];
    if (tid < CROWS) g[tid] = gate[b * CC + split * CROWS + tid];
    __syncthreads();
    const int n4 = npart * 256 + tid;   // f4 index within row
    const f4* xb = (const f4*)(x + ((size_t)b * CC + (size_t)split * CROWS) * NN);
    f4 s = {0.f, 0.f, 0.f, 0.f};
    f4 m = {-INFINITY, -INFINITY, -INFINITY, -INFINITY};
    #pragma unroll 8
    for (int c = 0; c < CROWS; ++c) {
        f4 v = xb[(size_t)c * N4 + n4];        // regular load: L3 hit, keep resident
        float gc = g[c];
        s.x = fmaf(gc, v.x, s.x);
        s.y = fmaf(gc, v.y, s.y);
        s.z = fmaf(gc, v.z, s.z);
        s.w = fmaf(gc, v.w, s.w);
        m.x = fmaxf(m.x, gc * v.x);
        m.y = fmaxf(m.y, gc * v.y);
        m.z = fmaxf(m.z, gc * v.z);
        m.w = fmaxf(m.w, gc * v.w);
    }
    const size_t o = (size_t)(b * SPLIT + split) * N4 + n4;
    ((f4*)psum)[o] = s;
    ((f4*)pmax)[o] = m;
}

// ---------------- K4: s = relu(BN(sw0*cx+sw1*cm)); exp(s-10); per-chunk sums ----------------
__global__ __launch_bounds__(256) void k4_exp(const float* __restrict__ psum,
                                              const float* __restrict__ pmax,
                                              const float* __restrict__ sw,
                                              const float* __restrict__ gamma,
                                              const float* __restrict__ beta,
                                              const float* __restrict__ rmean,
                                              const float* __restrict__ rvar,
                                              float* __restrict__ attexp,
                                              float* __restrict__ blksum,
                                              int b0) {
    const int chunk = blockIdx.x;   // 0..15
    const int b     = b0 + blockIdx.y;
    const int tid = threadIdx.x;
    const float sw0 = sw[0], sw1 = sw[1];
    const float scale = gamma[0] * rsqrtf(rvar[0] + 1e-5f);
    const float shift = beta[0] - rmean[0] * scale;
    const int i = chunk * 256 + tid;    // f4 index 0..4095
    const f4* ps = (const f4*)psum;
    const f4* pm = (const f4*)pmax;
    f4 ssum = {0.f, 0.f, 0.f, 0.f};
    f4 smax = {-INFINITY, -INFINITY, -INFINITY, -INFINITY};
    #pragma unroll
    for (int sp = 0; sp < SPLIT; ++sp) {
        f4 a = ps[(size_t)(b * SPLIT + sp) * N4 + i];
        f4 c = pm[(size_t)(b * SPLIT + sp) * N4 + i];
        ssum.x += a.x; ssum.y += a.y; ssum.z += a.z; ssum.w += a.w;
        smax.x = fmaxf(smax.x, c.x); smax.y = fmaxf(smax.y, c.y);
        smax.z = fmaxf(smax.z, c.z); smax.w = fmaxf(smax.w, c.w);
    }
    auto sval = [&](float su, float mx) -> float {
        float v = sw0 * mx + sw1 * (su * (1.0f / CC));
        v = fmaf(v, scale, shift);
        v = fmaxf(v, 0.f);                 // relu
        return expf(v - EXPSHIFT);
    };
    f4 e;
    e.x = sval(ssum.x, smax.x);
    e.y = sval(ssum.y, smax.y);
    e.z = sval(ssum.z, smax.z);
    e.w = sval(ssum.w, smax.w);
    ((f4*)attexp)[(size_t)b * N4 + i] = e;
    float lsum = e.x + e.y + e.z + e.w;
    for (int off = 32; off > 0; off >>= 1) lsum += __shfl_down(lsum, off, 64);
    __shared__ float red[4];
    if ((tid & 63) == 0) red[tid >> 6] = lsum;
    __syncthreads();
    if (tid == 0) blksum[b * 16 + chunk] = red[0] + red[1] + red[2] + red[3];
}

// ---------------- K6: out = attexp/tot * gate * x (x from L3; nt-store out) ----------------
__global__ __launch_bounds__(256) void k6_final(const float* __restrict__ x,
                                                const float* __restrict__ gate,
                                                const float* __restrict__ blksum,
                                                const float* __restrict__ attexp,
                                                float* __restrict__ out,
                                                int b0) {
    const int chunk = blockIdx.x;      // 0..15  (n-chunk of 256 f4)
    const int cgrp  = blockIdx.y;      // 0..CC/CG-1
    const int b     = b0 + blockIdx.z;
    const int tid = threadIdx.x;
    const int n4 = chunk * 256 + tid;
    const int row0 = b * CC + cgrp * CG;
    float tot = 0.f;
    #pragma unroll
    for (int j = 0; j < 16; ++j) tot += blksum[b * 16 + j];
    const float inv = 1.0f / tot;
    const f4 a = ((const f4*)attexp)[(size_t)b * N4 + n4];
    float gs[CG];
    #pragma unroll
    for (int r = 0; r < CG; ++r) gs[r] = gate[row0 + r] * inv;
    const f4* xp = (const f4*)x;
    f4* op = (f4*)out;
    f4 v[CG];
    #pragma unroll
    for (int r = 0; r < CG; ++r)
        v[r] = xp[(size_t)(row0 + r) * N4 + n4];   // should hit L3
    #pragma unroll
    for (int r = 0; r < CG; ++r) {
        f4 o;
        o.x = v[r].x * a.x * gs[r];
        o.y = v[r].y * a.y * gs[r];
        o.z = v[r].z * a.z * gs[r];
        o.w = v[r].w * a.w * gs[r];
        __builtin_nontemporal_store(o, &op[(size_t)(row0 + r) * N4 + n4]);
    }
}

extern "C" void kernel_launch(void* const* d_in, const int* in_sizes, int n_in,
                              void* d_out, int out_size, void* d_ws, size_t ws_size,
                              hipStream_t stream) {
    const float* x     = (const float*)d_in[0];
    const float* w1    = (const float*)d_in[1];
    const float* w2    = (const float*)d_in[2];
    const float* sw    = (const float*)d_in[3];
    const float* gamma = (const float*)d_in[4];
    const float* beta  = (const float*)d_in[5];
    const float* rmean = (const float*)d_in[6];
    const float* rvar  = (const float*)d_in[7];
    float* out = (float*)d_out;
    float* ws  = (float*)d_ws;

    float* meanp  = ws;                                  // B*C
    float* maxp   = meanp + 16384;                       // B*C
    float* gate   = maxp + 16384;                        // B*C
    float* psum   = gate + 16384;                        // B*SPLIT*N = 4194304
    float* pmax   = psum + (size_t)BB * SPLIT * NN;      // 4194304
    float* attexp = pmax + (size_t)BB * SPLIT * NN;      // B*N
    float* blksum = attexp + (size_t)BB * NN;            // B*16

    for (int g = 0; g < NGROUPS; ++g) {
        const int b0 = g * GROUP;
        k1_pool<<<GROUP * CC, 256, 0, stream>>>(x, meanp, maxp, b0);
        k2_gate<<<GROUP, 1024, 0, stream>>>(meanp, maxp, w1, w2, gate, b0);
        dim3 g3(NSPL, SPLIT, GROUP);
        k3_spatial<<<g3, 256, 0, stream>>>(x, gate, psum, pmax, b0);
        dim3 g4(16, GROUP);
        k4_exp<<<g4, 256, 0, stream>>>(psum, pmax, sw, gamma, beta, rmean, rvar, attexp, blksum, b0);
        dim3 g6(16, CC / CG, GROUP);
        k6_final<<<g6, 256, 0, stream>>>(x, gate, blksum, attexp, out, b0);
    }
}

// Round 8
// 731.978 us; speedup vs baseline: 1.5887x; 1.5887x over previous
//
#include <hip/hip_runtime.h>
#include <math.h>

#define BB 16
#define CC 1024
#define NN 16384
#define HID 128            // C / RATIO
#define SPLIT 8            // c-groups in k3/k4 partials
#define CROWS (CC/SPLIT)   // 128 rows per group
#define NSPL 2             // n-halves in k3
#define N4 (NN/4)          // 4096 float4 per row
#define EXPSHIFT 10.0f     // uniform shift inside softmax (exact math)
#define CG 8               // c-rows per block in k6

typedef float f4 __attribute__((ext_vector_type(4)));   // native vector for nontemporal builtins

// ---------------- K1: per-(b,c) mean & max over N ----------------
__global__ __launch_bounds__(256) void k1_pool(const float* __restrict__ x,
                                               float* __restrict__ meanp,
                                               float* __restrict__ maxp) {
    const int row = blockIdx.x;                 // b*C + c
    const int tid = threadIdx.x;
    const f4* xr = (const f4*)(x + (size_t)row * NN);
    float s = 0.f, m = -INFINITY;
    #pragma unroll
    for (int i = 0; i < 16; ++i) {
        f4 v = __builtin_nontemporal_load(&xr[tid + i * 256]);
        s += v.x + v.y + v.z + v.w;
        m = fmaxf(m, fmaxf(fmaxf(v.x, v.y), fmaxf(v.z, v.w)));
    }
    __shared__ float ss[4], sm[4];
    for (int off = 32; off > 0; off >>= 1) {
        s += __shfl_down(s, off, 64);
        m = fmaxf(m, __shfl_down(m, off, 64));
    }
    const int wave = tid >> 6, lane = tid & 63;
    if (lane == 0) { ss[wave] = s; sm[wave] = m; }
    __syncthreads();
    if (tid == 0) {
        float fs = ss[0] + ss[1] + ss[2] + ss[3];
        float fm = fmaxf(fmaxf(sm[0], sm[1]), fmaxf(sm[2], sm[3]));
        meanp[row] = fs * (1.0f / NN);
        maxp[row]  = fm;
    }
}

// ---------------- K2: shared MLP -> gate (1024 threads, 4-way split dots) ----------------
__global__ __launch_bounds__(1024) void k2_gate(const float* __restrict__ meanp,
                                                const float* __restrict__ maxp,
                                                const float* __restrict__ w1,
                                                const float* __restrict__ w2,
                                                float* __restrict__ gate) {
    const int b = blockIdx.x;
    const int tid = threadIdx.x;
    __shared__ float sv[2][CC];
    __shared__ float hh[2][HID];
    __shared__ float h[HID];
    if (tid < CC) {
        sv[0][tid] = meanp[b * CC + tid];
        sv[1][tid] = maxp[b * CC + tid];
    }
    __syncthreads();
    {
        const int slot = tid >> 2;       // 0..255
        const int part = tid & 3;        // 0..3
        const int src  = slot >> 7;      // 0..1
        const int r    = slot & 127;
        const float* w1r = w1 + (size_t)r * CC;
        const float* svp = sv[src];
        float acc = 0.f;
        const int c0 = part * 256;
        #pragma unroll 8
        for (int c = c0; c < c0 + 256; ++c) acc = fmaf(w1r[c], svp[c], acc);
        acc += __shfl_xor(acc, 1, 64);
        acc += __shfl_xor(acc, 2, 64);
        if (part == 0) hh[src][r] = fmaxf(acc, 0.f);   // relu
    }
    __syncthreads();
    if (tid < HID) h[tid] = hh[0][tid] + hh[1][tid];
    __syncthreads();
    {
        const float* w2r = w2 + (size_t)tid * HID;
        float a = 0.f;
        #pragma unroll
        for (int r = 0; r < HID; ++r) a = fmaf(w2r[r], h[r], a);
        gate[b * CC + tid] = 1.0f / (1.0f + expf(-a));  // sigmoid
    }
}

// ---------------- K3: spatial weighted sum/max over C — contiguous streaming ----------------
// block = (nhalf, split, b), 1024 threads; streams 128 rows x 32KB contiguous windows;
// accumulators in registers (2x f4 sum + 2x f4 max per thread).
__global__ __launch_bounds__(1024) void k3_spatial(const float* __restrict__ x,
                                                   const float* __restrict__ gate,
                                                   float* __restrict__ psum,
                                                   float* __restrict__ pmax) {
    const int nhalf = blockIdx.x;   // 0..NSPL-1
    const int split = blockIdx.y;   // 0..SPLIT-1
    const int b     = blockIdx.z;   // 0..B-1
    const int tid = threadIdx.x;    // 0..1023
    __shared__ float g[CROWS];
    if (tid < CROWS) g[tid] = gate[b * CC + split * CROWS + tid];
    __syncthreads();
    const f4* xb = (const f4*)(x + ((size_t)b * CC + (size_t)split * CROWS) * NN);
    const size_t nbase = (size_t)nhalf * 2048 + tid;   // float4 index of j=0 slot
    f4 s0 = {0.f, 0.f, 0.f, 0.f}, s1 = {0.f, 0.f, 0.f, 0.f};
    f4 m0 = {-INFINITY, -INFINITY, -INFINITY, -INFINITY};
    f4 m1 = {-INFINITY, -INFINITY, -INFINITY, -INFINITY};
    #pragma unroll 4
    for (int c = 0; c < CROWS; ++c) {
        const float gc = g[c];
        f4 v0 = __builtin_nontemporal_load(&xb[(size_t)c * N4 + nbase]);
        f4 v1 = __builtin_nontemporal_load(&xb[(size_t)c * N4 + nbase + 1024]);
        s0.x = fmaf(gc, v0.x, s0.x); s0.y = fmaf(gc, v0.y, s0.y);
        s0.z = fmaf(gc, v0.z, s0.z); s0.w = fmaf(gc, v0.w, s0.w);
        s1.x = fmaf(gc, v1.x, s1.x); s1.y = fmaf(gc, v1.y, s1.y);
        s1.z = fmaf(gc, v1.z, s1.z); s1.w = fmaf(gc, v1.w, s1.w);
        m0.x = fmaxf(m0.x, gc * v0.x); m0.y = fmaxf(m0.y, gc * v0.y);
        m0.z = fmaxf(m0.z, gc * v0.z); m0.w = fmaxf(m0.w, gc * v0.w);
        m1.x = fmaxf(m1.x, gc * v1.x); m1.y = fmaxf(m1.y, gc * v1.y);
        m1.z = fmaxf(m1.z, gc * v1.z); m1.w = fmaxf(m1.w, gc * v1.w);
    }
    const size_t o = (size_t)(b * SPLIT + split) * N4 + nbase;
    ((f4*)psum)[o] = s0;
    ((f4*)psum)[o + 1024] = s1;
    ((f4*)pmax)[o] = m0;
    ((f4*)pmax)[o + 1024] = m1;
}

// ---------------- K4: s = relu(BN(sw0*cx+sw1*cm)); exp(s-10); partial sums ----------------
__global__ __launch_bounds__(256) void k4_exp(const float* __restrict__ psum,
                                              const float* __restrict__ pmax,
                                              const float* __restrict__ sw,
                                              const float* __restrict__ gamma,
                                              const float* __restrict__ beta,
                                              const float* __restrict__ rmean,
                                              const float* __restrict__ rvar,
                                              float* __restrict__ attexp,
                                              float* __restrict__ blksum) {
    const int chunk = blockIdx.x;   // 0..15
    const int b     = blockIdx.y;
    const int tid = threadIdx.x;
    const float sw0 = sw[0], sw1 = sw[1];
    const float scale = gamma[0] * rsqrtf(rvar[0] + 1e-5f);
    const float shift = beta[0] - rmean[0] * scale;
    const int i = chunk * 256 + tid;    // float4 index in 0..4095
    const f4* ps = (const f4*)psum;
    const f4* pm = (const f4*)pmax;
    f4 ssum = {0.f, 0.f, 0.f, 0.f};
    f4 smax = {-INFINITY, -INFINITY, -INFINITY, -INFINITY};
    #pragma unroll
    for (int sp = 0; sp < SPLIT; ++sp) {
        f4 a = ps[(size_t)(b * SPLIT + sp) * N4 + i];
        f4 c = pm[(size_t)(b * SPLIT + sp) * N4 + i];
        ssum.x += a.x; ssum.y += a.y; ssum.z += a.z; ssum.w += a.w;
        smax.x = fmaxf(smax.x, c.x); smax.y = fmaxf(smax.y, c.y);
        smax.z = fmaxf(smax.z, c.z); smax.w = fmaxf(smax.w, c.w);
    }
    auto sval = [&](float su, float mx) -> float {
        float v = sw0 * mx + sw1 * (su * (1.0f / CC));
        v = fmaf(v, scale, shift);
        v = fmaxf(v, 0.f);                 // relu
        return expf(v - EXPSHIFT);
    };
    f4 e;
    e.x = sval(ssum.x, smax.x);
    e.y = sval(ssum.y, smax.y);
    e.z = sval(ssum.z, smax.z);
    e.w = sval(ssum.w, smax.w);
    ((f4*)attexp)[(size_t)b * N4 + i] = e;
    float lsum = e.x + e.y + e.z + e.w;
    for (int off = 32; off > 0; off >>= 1) lsum += __shfl_down(lsum, off, 64);
    __shared__ float red[4];
    if ((tid & 63) == 0) red[tid >> 6] = lsum;
    __syncthreads();
    if (tid == 0) blksum[b * 16 + chunk] = red[0] + red[1] + red[2] + red[3];
}

// ---------------- K5: per-row scale = gate[row] / sum_b ----------------
__global__ __launch_bounds__(256) void k5_gscale(const float* __restrict__ gate,
                                                 const float* __restrict__ blksum,
                                                 float* __restrict__ gscale) {
    const int row = blockIdx.x * 256 + threadIdx.x;   // 0..16383
    const int b = row >> 10;
    float tot = 0.f;
    #pragma unroll
    for (int j = 0; j < 16; ++j) tot += blksum[b * 16 + j];
    gscale[row] = gate[row] / tot;
}

// ---------------- K6: out = attexp * gscale * x (CG rows share attexp; nt-store) ----------------
__global__ __launch_bounds__(256) void k6_final(const float* __restrict__ x,
                                                const float* __restrict__ gscale,
                                                const float* __restrict__ attexp,
                                                float* __restrict__ out) {
    const int chunk = blockIdx.x;      // 0..15  (n-chunk of 256 float4)
    const int cgrp  = blockIdx.y;      // 0..CC/CG-1
    const int b     = blockIdx.z;      // 0..BB-1
    const int tid = threadIdx.x;
    const int n4 = chunk * 256 + tid;
    const int row0 = b * CC + cgrp * CG;
    const f4 a = ((const f4*)attexp)[(size_t)b * N4 + n4];
    float gs[CG];
    #pragma unroll
    for (int r = 0; r < CG; ++r) gs[r] = gscale[row0 + r];
    const f4* xp = (const f4*)x;
    f4* op = (f4*)out;
    f4 v[CG];
    #pragma unroll
    for (int r = 0; r < CG; ++r)
        v[r] = __builtin_nontemporal_load(&xp[(size_t)(row0 + r) * N4 + n4]);
    #pragma unroll
    for (int r = 0; r < CG; ++r) {
        f4 o;
        o.x = v[r].x * a.x * gs[r];
        o.y = v[r].y * a.y * gs[r];
        o.z = v[r].z * a.z * gs[r];
        o.w = v[r].w * a.w * gs[r];
        __builtin_nontemporal_store(o, &op[(size_t)(row0 + r) * N4 + n4]);
    }
}

extern "C" void kernel_launch(void* const* d_in, const int* in_sizes, int n_in,
                              void* d_out, int out_size, void* d_ws, size_t ws_size,
                              hipStream_t stream) {
    const float* x     = (const float*)d_in[0];
    const float* w1    = (const float*)d_in[1];
    const float* w2    = (const float*)d_in[2];
    const float* sw    = (const float*)d_in[3];
    const float* gamma = (const float*)d_in[4];
    const float* beta  = (const float*)d_in[5];
    const float* rmean = (const float*)d_in[6];
    const float* rvar  = (const float*)d_in[7];
    float* out = (float*)d_out;
    float* ws  = (float*)d_ws;

    float* meanp  = ws;                                  // 16384
    float* maxp   = meanp + 16384;                       // 16384
    float* gate   = maxp + 16384;                        // 16384
    float* gscale = gate + 16384;                        // 16384
    float* psum   = gscale + 16384;                      // B*SPLIT*N = 2097152
    float* pmax   = psum + (size_t)BB * SPLIT * NN;      // 2097152
    float* attexp = pmax + (size_t)BB * SPLIT * NN;      // B*N = 262144
    float* blksum = attexp + (size_t)BB * NN;            // 256

    k1_pool<<<BB * CC, 256, 0, stream>>>(x, meanp, maxp);
    k2_gate<<<BB, 1024, 0, stream>>>(meanp, maxp, w1, w2, gate);
    dim3 g3(NSPL, SPLIT, BB);
    k3_spatial<<<g3, 1024, 0, stream>>>(x, gate, psum, pmax);
    dim3 g4(16, BB);
    k4_exp<<<g4, 256, 0, stream>>>(psum, pmax, sw, gamma, beta, rmean, rvar, attexp, blksum);
    k5_gscale<<<BB * CC / 256, 256, 0, stream>>>(gate, blksum, gscale);
    dim3 g6(16, CC / CG, BB);
    k6_final<<<g6, 256, 0, stream>>>(x, gscale, attexp, out);
}